// Round 2
// baseline (2501.732 us; speedup 1.0000x reference)
//
#include <hip/hip_runtime.h>
#include <hip/hip_bf16.h>

// ---------------------------------------------------------------------------
// TMSwinBlock: LN1 -> shift+window -> QKV -> windowed MHA (+rel bias, +mask)
//  -> proj -> unshift + residual -> LN2 -> GEGLU MLP -> residual
// Wire dtype: float32 (per reference). Intermediates in d_ws: bf16.
// fp32 accumulation everywhere; MFMA 16x16x32_bf16 for the 4 dense GEMMs.
// Verified layouts: A[m=lane&15][k=quad*8+j], B^T same, D row=quad*4+r col=lane&15.
// ---------------------------------------------------------------------------

typedef unsigned short u16;
typedef __attribute__((ext_vector_type(8))) short short8;
typedef __attribute__((ext_vector_type(4))) float f32x4;

#define T_TOK 200704   // B * H * W = 64*56*56
#define CDIM  128
#define NHEAD 4
#define HD    32
#define NTOK  49       // tokens per window
#define WS    7
#define SHIFT 3
#define HID   512

__device__ __forceinline__ float bf2f(u16 v) {
    return __uint_as_float(((unsigned int)v) << 16);
}
__device__ __forceinline__ u16 f2bf(float f) {
    unsigned int u = __float_as_uint(f);
    unsigned int r = 0x7FFFu + ((u >> 16) & 1u);
    return (u16)((u + r) >> 16);
}

// ---------------------------------------------------------------------------
// LN1 over C=128, fp32 input, bf16 output rows in shifted-window order.
// One wave per token (2 ch/lane).
// ---------------------------------------------------------------------------
__global__ __launch_bounds__(256) void ln1_kernel(
    const float* __restrict__ xin, const float* __restrict__ gam,
    const float* __restrict__ bet, u16* __restrict__ outp)
{
    int wave = threadIdx.x >> 6, lane = threadIdx.x & 63;
    int t = blockIdx.x * 4 + wave;          // output row (window order)
    int win = t / NTOK, n = t - win * NTOK;
    int b = win >> 6, wi = win & 63;
    int hp = (wi >> 3) * WS + n / WS;
    int wp = (wi & 7) * WS + n % WS;
    int h = hp + SHIFT; if (h >= 56) h -= 56;
    int w = wp + SHIFT; if (w >= 56) w -= 56;
    int src = b * 3136 + h * 56 + w;
    const float* xr = xin + (size_t)src * CDIM;
    int c0 = lane * 2;
    float x0 = xr[c0], x1 = xr[c0 + 1];
    float s = x0 + x1;
    #pragma unroll
    for (int m = 1; m < 64; m <<= 1) s += __shfl_xor(s, m);
    float mean = s * (1.0f / 128.0f);
    float d0 = x0 - mean, d1 = x1 - mean;
    float v = d0 * d0 + d1 * d1;
    #pragma unroll
    for (int m = 1; m < 64; m <<= 1) v += __shfl_xor(v, m);
    float rstd = rsqrtf(v * (1.0f / 128.0f) + 1e-5f);
    float y0 = d0 * rstd * gam[c0]     + bet[c0];
    float y1 = d1 * rstd * gam[c0 + 1] + bet[c0 + 1];
    u16 pair[2] = { f2bf(y0), f2bf(y1) };
    *(unsigned int*)(outp + (size_t)t * CDIM + c0) = *(unsigned int*)pair;
}

// ---------------------------------------------------------------------------
// LN2 over C=128, bf16 input (x1 in ws), bf16 output, identity row map.
// ---------------------------------------------------------------------------
__global__ __launch_bounds__(256) void ln2_kernel(
    const u16* __restrict__ xin, const float* __restrict__ gam,
    const float* __restrict__ bet, u16* __restrict__ outp)
{
    int wave = threadIdx.x >> 6, lane = threadIdx.x & 63;
    int t = blockIdx.x * 4 + wave;
    const u16* xr = xin + (size_t)t * CDIM;
    int c0 = lane * 2;
    float x0 = bf2f(xr[c0]), x1 = bf2f(xr[c0 + 1]);
    float s = x0 + x1;
    #pragma unroll
    for (int m = 1; m < 64; m <<= 1) s += __shfl_xor(s, m);
    float mean = s * (1.0f / 128.0f);
    float d0 = x0 - mean, d1 = x1 - mean;
    float v = d0 * d0 + d1 * d1;
    #pragma unroll
    for (int m = 1; m < 64; m <<= 1) v += __shfl_xor(v, m);
    float rstd = rsqrtf(v * (1.0f / 128.0f) + 1e-5f);
    float y0 = d0 * rstd * gam[c0]     + bet[c0];
    float y1 = d1 * rstd * gam[c0 + 1] + bet[c0 + 1];
    u16 pair[2] = { f2bf(y0), f2bf(y1) };
    *(unsigned int*)(outp + (size_t)t * CDIM + c0) = *(unsigned int*)pair;
}

// ---------------------------------------------------------------------------
// QKV GEMM: win[T,128](bf16) @ w_qkv[128,384](fp32->bf16) + b_qkv, scattered
// into q/k/v ws buffers laid out [4096 win][4 head][49 n][32 hd] (bf16).
// q gets *scale folded in. Block: 64(M) x 64(N), 4 waves.
// ---------------------------------------------------------------------------
__global__ __launch_bounds__(256) void qkv_gemm(
    const u16* __restrict__ A, const float* __restrict__ W,
    const float* __restrict__ bias,
    u16* __restrict__ qb, u16* __restrict__ kb, u16* __restrict__ vb)
{
    __shared__ short As[64 * 128];
    __shared__ short Bs[64 * 128];
    int tid = threadIdx.x;
    int m0 = blockIdx.x * 64, n0 = blockIdx.y * 64;
    #pragma unroll
    for (int i = 0; i < 4; i++) {                 // A tile: 1024 x 16B chunks
        int chunk = i * 256 + tid;
        int row = chunk >> 4, c8 = chunk & 15;
        *(int4*)(As + row * 128 + c8 * 8) =
            *(const int4*)(A + (size_t)(m0 + row) * 128 + c8 * 8);
    }
    #pragma unroll
    for (int i = 0; i < 32; i++) {                // B^T tile: Bs[n][k]=W[k][n0+n]
        int e = i * 256 + tid;
        int kk = e & 127, n = e >> 7;
        Bs[n * 128 + kk] = (short)f2bf(W[kk * 384 + n0 + n]);
    }
    __syncthreads();
    int wave = tid >> 6, lane = tid & 63;
    int lr = lane & 15, quad = lane >> 4;
    f32x4 acc[4];
    #pragma unroll
    for (int i = 0; i < 4; i++) { acc[i][0] = 0.f; acc[i][1] = 0.f; acc[i][2] = 0.f; acc[i][3] = 0.f; }
    #pragma unroll
    for (int ks = 0; ks < 4; ks++) {
        short8 a = *(const short8*)(As + (wave * 16 + lr) * 128 + ks * 32 + quad * 8);
        #pragma unroll
        for (int nt = 0; nt < 4; nt++) {
            short8 b = *(const short8*)(Bs + (nt * 16 + lr) * 128 + ks * 32 + quad * 8);
            acc[nt] = __builtin_amdgcn_mfma_f32_16x16x32_bf16(a, b, acc[nt], 0, 0, 0);
        }
    }
    const float scale = 0.17677669529663687f;  // HD^-0.5
    #pragma unroll
    for (int nt = 0; nt < 4; nt++) {
        int col = n0 + nt * 16 + lr;
        int which = col >> 7, head = (col >> 5) & 3, hd = col & 31;
        u16* dst = (which == 0) ? qb : (which == 1 ? kb : vb);
        float bv = bias[col];
        #pragma unroll
        for (int r = 0; r < 4; r++) {
            int m = m0 + wave * 16 + quad * 4 + r;
            int win = m / NTOK, n = m - win * NTOK;
            float v = acc[nt][r] + bv;
            if (which == 0) v *= scale;
            dst[(size_t)((win * 4 + head) * NTOK + n) * HD + hd] = f2bf(v);
        }
    }
}

// ---------------------------------------------------------------------------
// Attention: one block per (window, head). S = q@k^T + rel_bias + mask,
// softmax rows, O = P@v. All VALU fp32.
// Output o (bf16, window order): row = win*49+qi, col = head*32+hd.
// ---------------------------------------------------------------------------
__global__ __launch_bounds__(256) void attn_kernel(
    const u16* __restrict__ qb, const u16* __restrict__ kb,
    const u16* __restrict__ vb, const float* __restrict__ rel_bias,
    const int* __restrict__ rel_index, const float* __restrict__ mask,
    u16* __restrict__ ob)
{
    __shared__ float qs[49 * 32], ksm[49 * 32], vs[49 * 32];
    __shared__ float S[49 * 52];
    int wh = blockIdx.x;                 // win*4 + head
    int win = wh >> 2, head = wh & 3;
    int tid = threadIdx.x;
    const u16* qp = qb + (size_t)wh * 49 * 32;
    const u16* kp = kb + (size_t)wh * 49 * 32;
    const u16* vp = vb + (size_t)wh * 49 * 32;
    for (int e = tid; e < 49 * 32; e += 256) {
        qs[e] = bf2f(qp[e]); ksm[e] = bf2f(kp[e]); vs[e] = bf2f(vp[e]);
    }
    __syncthreads();
    const float* mrow = mask + (size_t)(win & 63) * 49 * 49;
    for (int e = tid; e < 49 * 49; e += 256) {
        int qi = e / 49, kj = e - qi * 49;
        const float* qq = qs + qi * 32;
        const float* kk = ksm + kj * 32;
        float s = 0.f;
        #pragma unroll
        for (int d = 0; d < 32; d++) s += qq[d] * kk[d];
        s += rel_bias[rel_index[e] * 4 + head];
        s += mrow[e];
        S[qi * 52 + kj] = s;
    }
    __syncthreads();
    int wave = tid >> 6, lane = tid & 63;
    for (int qi = wave; qi < 49; qi += 4) {
        float v = (lane < 49) ? S[qi * 52 + lane] : -1e30f;
        float mx = v;
        #pragma unroll
        for (int m = 1; m < 64; m <<= 1) mx = fmaxf(mx, __shfl_xor(mx, m));
        float e = (lane < 49) ? __expf(v - mx) : 0.f;
        float sum = e;
        #pragma unroll
        for (int m = 1; m < 64; m <<= 1) sum += __shfl_xor(sum, m);
        if (lane < 49) S[qi * 52 + lane] = e / sum;
    }
    __syncthreads();
    for (int e = tid; e < 49 * 32; e += 256) {
        int qi = e >> 5, hd = e & 31;
        const float* pr = S + qi * 52;
        float s = 0.f;
        #pragma unroll
        for (int kj = 0; kj < 49; kj++) s += pr[kj] * vs[kj * 32 + hd];
        ob[(size_t)(win * NTOK + qi) * CDIM + head * HD + hd] = f2bf(s);
    }
}

// ---------------------------------------------------------------------------
// Proj GEMM + window-reverse + un-shift + residual:
// x1(bf16) = x(fp32) + unshift(o(bf16) @ w_proj(fp32->bf16) + b_proj)
// ---------------------------------------------------------------------------
__global__ __launch_bounds__(256) void proj_gemm(
    const u16* __restrict__ A, const float* __restrict__ W,
    const float* __restrict__ bias, const float* __restrict__ xres,
    u16* __restrict__ x1)
{
    __shared__ short As[64 * 128];
    __shared__ short Bs[64 * 128];
    int tid = threadIdx.x;
    int m0 = blockIdx.x * 64, n0 = blockIdx.y * 64;
    #pragma unroll
    for (int i = 0; i < 4; i++) {
        int chunk = i * 256 + tid;
        int row = chunk >> 4, c8 = chunk & 15;
        *(int4*)(As + row * 128 + c8 * 8) =
            *(const int4*)(A + (size_t)(m0 + row) * 128 + c8 * 8);
    }
    #pragma unroll
    for (int i = 0; i < 32; i++) {
        int e = i * 256 + tid;
        int kk = e & 127, n = e >> 7;
        Bs[n * 128 + kk] = (short)f2bf(W[kk * 128 + n0 + n]);
    }
    __syncthreads();
    int wave = tid >> 6, lane = tid & 63;
    int lr = lane & 15, quad = lane >> 4;
    f32x4 acc[4];
    #pragma unroll
    for (int i = 0; i < 4; i++) { acc[i][0] = 0.f; acc[i][1] = 0.f; acc[i][2] = 0.f; acc[i][3] = 0.f; }
    #pragma unroll
    for (int ks = 0; ks < 4; ks++) {
        short8 a = *(const short8*)(As + (wave * 16 + lr) * 128 + ks * 32 + quad * 8);
        #pragma unroll
        for (int nt = 0; nt < 4; nt++) {
            short8 b = *(const short8*)(Bs + (nt * 16 + lr) * 128 + ks * 32 + quad * 8);
            acc[nt] = __builtin_amdgcn_mfma_f32_16x16x32_bf16(a, b, acc[nt], 0, 0, 0);
        }
    }
    #pragma unroll
    for (int nt = 0; nt < 4; nt++) {
        int col = n0 + nt * 16 + lr;
        float bv = bias[col];
        #pragma unroll
        for (int r = 0; r < 4; r++) {
            int m = m0 + wave * 16 + quad * 4 + r;   // window-order row
            int win = m / NTOK, n = m - win * NTOK;
            int b = win >> 6, wi = win & 63;
            int hp = (wi >> 3) * WS + n / WS;
            int wp = (wi & 7) * WS + n % WS;
            int h = hp + SHIFT; if (h >= 56) h -= 56;
            int w = wp + SHIFT; if (w >= 56) w -= 56;
            size_t tok = (size_t)b * 3136 + h * 56 + w;
            float v = acc[nt][r] + bv + xres[tok * CDIM + col];
            x1[tok * CDIM + col] = f2bf(v);
        }
    }
}

// ---------------------------------------------------------------------------
// MLP-in GEMM + GEGLU: y(bf16)[T,128] @ w_in(fp32->bf16)[128,1024] + b_in;
// fused(bf16) = gelu(val) * sigmoid(gate).
// ---------------------------------------------------------------------------
__global__ __launch_bounds__(256) void mlpin_gemm(
    const u16* __restrict__ A, const float* __restrict__ W,
    const float* __restrict__ bias, u16* __restrict__ fused)
{
    __shared__ short As[64 * 128];
    __shared__ short Bv[64 * 128];
    __shared__ short Bg[64 * 128];
    int tid = threadIdx.x;
    int m0 = blockIdx.x * 64, n0 = blockIdx.y * 64;
    #pragma unroll
    for (int i = 0; i < 4; i++) {
        int chunk = i * 256 + tid;
        int row = chunk >> 4, c8 = chunk & 15;
        *(int4*)(As + row * 128 + c8 * 8) =
            *(const int4*)(A + (size_t)(m0 + row) * 128 + c8 * 8);
    }
    #pragma unroll
    for (int i = 0; i < 32; i++) {
        int e = i * 256 + tid;
        int kk = e & 127, n = e >> 7;
        Bv[n * 128 + kk] = (short)f2bf(W[kk * 1024 + n0 + n]);
        Bg[n * 128 + kk] = (short)f2bf(W[kk * 1024 + 512 + n0 + n]);
    }
    __syncthreads();
    int wave = tid >> 6, lane = tid & 63;
    int lr = lane & 15, quad = lane >> 4;
    f32x4 av[4], ag[4];
    #pragma unroll
    for (int i = 0; i < 4; i++) {
        av[i][0]=0.f; av[i][1]=0.f; av[i][2]=0.f; av[i][3]=0.f;
        ag[i][0]=0.f; ag[i][1]=0.f; ag[i][2]=0.f; ag[i][3]=0.f;
    }
    #pragma unroll
    for (int ks = 0; ks < 4; ks++) {
        short8 a = *(const short8*)(As + (wave * 16 + lr) * 128 + ks * 32 + quad * 8);
        #pragma unroll
        for (int nt = 0; nt < 4; nt++) {
            short8 b1 = *(const short8*)(Bv + (nt * 16 + lr) * 128 + ks * 32 + quad * 8);
            av[nt] = __builtin_amdgcn_mfma_f32_16x16x32_bf16(a, b1, av[nt], 0, 0, 0);
            short8 b2 = *(const short8*)(Bg + (nt * 16 + lr) * 128 + ks * 32 + quad * 8);
            ag[nt] = __builtin_amdgcn_mfma_f32_16x16x32_bf16(a, b2, ag[nt], 0, 0, 0);
        }
    }
    #pragma unroll
    for (int nt = 0; nt < 4; nt++) {
        int col = n0 + nt * 16 + lr;
        float bv = bias[col];
        float bg = bias[512 + col];
        #pragma unroll
        for (int r = 0; r < 4; r++) {
            int m = m0 + wave * 16 + quad * 4 + r;
            float x = av[nt][r] + bv;
            float g = ag[nt][r] + bg;
            float t = tanhf(0.7978845608028654f * (x + 0.044715f * x * x * x));
            float gel = 0.5f * x * (1.f + t);
            float sig = 1.f / (1.f + __expf(-g));
            fused[(size_t)m * HID + col] = f2bf(gel * sig);
        }
    }
}

// ---------------------------------------------------------------------------
// MLP-core GEMM + residual:
// out(fp32) = x1(bf16) + fused(bf16)[T,512] @ w_core(fp32->bf16)[512,128] + b_core
// K=512 in 4 chunks of 128.
// ---------------------------------------------------------------------------
__global__ __launch_bounds__(256) void mlpcore_gemm(
    const u16* __restrict__ A, const float* __restrict__ W,
    const float* __restrict__ bias, const u16* __restrict__ x1,
    float* __restrict__ outp)
{
    __shared__ short As[64 * 128];
    __shared__ short Bs[64 * 128];
    int tid = threadIdx.x;
    int m0 = blockIdx.x * 64, n0 = blockIdx.y * 64;
    int wave = tid >> 6, lane = tid & 63;
    int lr = lane & 15, quad = lane >> 4;
    f32x4 acc[4];
    #pragma unroll
    for (int i = 0; i < 4; i++) { acc[i][0] = 0.f; acc[i][1] = 0.f; acc[i][2] = 0.f; acc[i][3] = 0.f; }
    for (int kc = 0; kc < 4; kc++) {
        #pragma unroll
        for (int i = 0; i < 4; i++) {
            int chunk = i * 256 + tid;
            int row = chunk >> 4, c8 = chunk & 15;
            *(int4*)(As + row * 128 + c8 * 8) =
                *(const int4*)(A + (size_t)(m0 + row) * HID + kc * 128 + c8 * 8);
        }
        #pragma unroll
        for (int i = 0; i < 32; i++) {
            int e = i * 256 + tid;
            int kk = e & 127, n = e >> 7;
            Bs[n * 128 + kk] = (short)f2bf(W[(kc * 128 + kk) * 128 + n0 + n]);
        }
        __syncthreads();
        #pragma unroll
        for (int ks = 0; ks < 4; ks++) {
            short8 a = *(const short8*)(As + (wave * 16 + lr) * 128 + ks * 32 + quad * 8);
            #pragma unroll
            for (int nt = 0; nt < 4; nt++) {
                short8 b = *(const short8*)(Bs + (nt * 16 + lr) * 128 + ks * 32 + quad * 8);
                acc[nt] = __builtin_amdgcn_mfma_f32_16x16x32_bf16(a, b, acc[nt], 0, 0, 0);
            }
        }
        __syncthreads();
    }
    #pragma unroll
    for (int nt = 0; nt < 4; nt++) {
        int col = n0 + nt * 16 + lr;
        float bv = bias[col];
        #pragma unroll
        for (int r = 0; r < 4; r++) {
            int m = m0 + wave * 16 + quad * 4 + r;
            float v = acc[nt][r] + bv + bf2f(x1[(size_t)m * CDIM + col]);
            outp[(size_t)m * CDIM + col] = v;
        }
    }
}

// ---------------------------------------------------------------------------
extern "C" void kernel_launch(void* const* d_in, const int* in_sizes, int n_in,
                              void* d_out, int out_size, void* d_ws, size_t ws_size,
                              hipStream_t stream)
{
    const float* x        = (const float*)d_in[0];
    const float* g1       = (const float*)d_in[1];
    const float* b1       = (const float*)d_in[2];
    const float* w_qkv    = (const float*)d_in[3];
    const float* b_qkv    = (const float*)d_in[4];
    const float* rel_bias = (const float*)d_in[5];
    const float* w_proj   = (const float*)d_in[6];
    const float* b_proj   = (const float*)d_in[7];
    const float* g2       = (const float*)d_in[8];
    const float* b2       = (const float*)d_in[9];
    const float* w_in     = (const float*)d_in[10];
    const float* b_in     = (const float*)d_in[11];
    const float* w_core   = (const float*)d_in[12];
    const float* b_core   = (const float*)d_in[13];
    const float* attn_mask = (const float*)d_in[14];
    const int*   rel_index = (const int*)d_in[15];
    float* outp = (float*)d_out;

    char* ws = (char*)d_ws;
    const size_t sz128 = (size_t)T_TOK * CDIM * sizeof(u16);   // 51,380,224 B
    u16* qb    = (u16*)(ws);
    u16* kb    = (u16*)(ws + sz128);
    u16* vb    = (u16*)(ws + 2 * sz128);
    u16* ob    = (u16*)(ws + 3 * sz128);
    u16* fused = (u16*)(ws);               // reuses q/k/v/o region (dead by then)
    u16* ybuf  = (u16*)(ws + 4 * sz128);   // LN1 out (window order), then LN2 out
    u16* x1    = (u16*)(ws + 5 * sz128);
    // total ws use: 6*sz128 = 308,281,344 B

    ln1_kernel<<<T_TOK / 4, 256, 0, stream>>>(x, g1, b1, ybuf);
    qkv_gemm<<<dim3(T_TOK / 64, 6), 256, 0, stream>>>(ybuf, w_qkv, b_qkv, qb, kb, vb);
    attn_kernel<<<4096 * 4, 256, 0, stream>>>(qb, kb, vb, rel_bias, rel_index, attn_mask, ob);
    proj_gemm<<<dim3(T_TOK / 64, 2), 256, 0, stream>>>(ob, w_proj, b_proj, x, x1);
    ln2_kernel<<<T_TOK / 4, 256, 0, stream>>>(x1, g2, b2, ybuf);
    mlpin_gemm<<<dim3(T_TOK / 64, 8), 256, 0, stream>>>(ybuf, w_in, b_in, fused);
    mlpcore_gemm<<<dim3(T_TOK / 64, 2), 256, 0, stream>>>(fused, w_core, b_core, x1, outp);
}

// Round 3
// 1061.383 us; speedup vs baseline: 2.3570x; 2.3570x over previous
//
#include <hip/hip_runtime.h>
#include <hip/hip_bf16.h>

// ---------------------------------------------------------------------------
// TMSwinBlock v3. Fixes vs v2 (943us mlpin, 1e8 bank conflicts, MfmaUtil 2.3%):
//  - prep kernel: all weights -> bf16 B^T [n][k] once (coalesced staging after)
//  - LDS rows padded to 136 shorts (272B): 16-way frag-read conflicts -> 2-way (free)
//  - 128-row blocks, n0-loop inside kernel: A staged once, A-frags in regs,
//    each wave owns 2x 16-row groups (mr=2) -> B frags reused 2x
//  - attn: q/k/v LDS padded to stride 33 (was 32 = fully bank-serialized dots)
// ---------------------------------------------------------------------------

typedef unsigned short u16;
typedef __attribute__((ext_vector_type(8))) short short8;
typedef __attribute__((ext_vector_type(4))) float f32x4;

#define T_TOK 200704   // 64*56*56
#define CDIM  128
#define NTOK  49
#define WSZ   7
#define SHIFT 3
#define HID   512
#define PAD   136      // LDS row stride in shorts for 128-wide K tiles

__device__ __forceinline__ float bf2f(u16 v) {
    return __uint_as_float(((unsigned int)v) << 16);
}
__device__ __forceinline__ u16 f2bf(float f) {
    unsigned int u = __float_as_uint(f);
    unsigned int r = 0x7FFFu + ((u >> 16) & 1u);
    return (u16)((u + r) >> 16);
}

// ---------------------------------------------------------------------------
// Weight prep: fp32 W[k][n] -> bf16 WT[n][k], for all 4 weight matrices.
// Reads fully coalesced (linear over source).
// ---------------------------------------------------------------------------
__global__ __launch_bounds__(256) void prep_weights(
    const float* __restrict__ w_qkv, const float* __restrict__ w_proj,
    const float* __restrict__ w_in,  const float* __restrict__ w_core,
    u16* __restrict__ qkvT, u16* __restrict__ projT,
    u16* __restrict__ inT,  u16* __restrict__ coreT)
{
    int g = blockIdx.x * 256 + threadIdx.x;
    if (g < 49152) {                       // w_qkv 128x384
        int k = g / 384, n = g % 384;
        qkvT[n * 128 + k] = f2bf(w_qkv[g]);
    } else if (g < 65536) {                // w_proj 128x128
        int h = g - 49152; int k = h / 128, n = h % 128;
        projT[n * 128 + k] = f2bf(w_proj[h]);
    } else if (g < 196608) {               // w_in 128x1024
        int h = g - 65536; int k = h / 1024, n = h % 1024;
        inT[n * 128 + k] = f2bf(w_in[h]);
    } else {                               // w_core 512x128
        int h = g - 196608; int k = h / 128, n = h % 128;
        coreT[n * 512 + k] = f2bf(w_core[h]);
    }
}

// ---------------------------------------------------------------------------
// LN1: fp32 x -> bf16 rows in shifted-window order. One wave per token.
// ---------------------------------------------------------------------------
__global__ __launch_bounds__(256) void ln1_kernel(
    const float* __restrict__ xin, const float* __restrict__ gam,
    const float* __restrict__ bet, u16* __restrict__ outp)
{
    int wave = threadIdx.x >> 6, lane = threadIdx.x & 63;
    int t = blockIdx.x * 4 + wave;
    int win = t / NTOK, n = t - win * NTOK;
    int b = win >> 6, wi = win & 63;
    int hp = (wi >> 3) * WSZ + n / WSZ;
    int wp = (wi & 7) * WSZ + n % WSZ;
    int h = hp + SHIFT; if (h >= 56) h -= 56;
    int w = wp + SHIFT; if (w >= 56) w -= 56;
    int src = b * 3136 + h * 56 + w;
    const float* xr = xin + (size_t)src * CDIM;
    int c0 = lane * 2;
    float x0 = xr[c0], x1 = xr[c0 + 1];
    float s = x0 + x1;
    #pragma unroll
    for (int m = 1; m < 64; m <<= 1) s += __shfl_xor(s, m);
    float mean = s * (1.0f / 128.0f);
    float d0 = x0 - mean, d1 = x1 - mean;
    float v = d0 * d0 + d1 * d1;
    #pragma unroll
    for (int m = 1; m < 64; m <<= 1) v += __shfl_xor(v, m);
    float rstd = rsqrtf(v * (1.0f / 128.0f) + 1e-5f);
    float y0 = d0 * rstd * gam[c0]     + bet[c0];
    float y1 = d1 * rstd * gam[c0 + 1] + bet[c0 + 1];
    u16 pair[2] = { f2bf(y0), f2bf(y1) };
    *(unsigned int*)(outp + (size_t)t * CDIM + c0) = *(unsigned int*)pair;
}

// ---------------------------------------------------------------------------
// LN2: bf16 x1 -> bf16, identity row map.
// ---------------------------------------------------------------------------
__global__ __launch_bounds__(256) void ln2_kernel(
    const u16* __restrict__ xin, const float* __restrict__ gam,
    const float* __restrict__ bet, u16* __restrict__ outp)
{
    int wave = threadIdx.x >> 6, lane = threadIdx.x & 63;
    int t = blockIdx.x * 4 + wave;
    const u16* xr = xin + (size_t)t * CDIM;
    int c0 = lane * 2;
    float x0 = bf2f(xr[c0]), x1 = bf2f(xr[c0 + 1]);
    float s = x0 + x1;
    #pragma unroll
    for (int m = 1; m < 64; m <<= 1) s += __shfl_xor(s, m);
    float mean = s * (1.0f / 128.0f);
    float d0 = x0 - mean, d1 = x1 - mean;
    float v = d0 * d0 + d1 * d1;
    #pragma unroll
    for (int m = 1; m < 64; m <<= 1) v += __shfl_xor(v, m);
    float rstd = rsqrtf(v * (1.0f / 128.0f) + 1e-5f);
    float y0 = d0 * rstd * gam[c0]     + bet[c0];
    float y1 = d1 * rstd * gam[c0 + 1] + bet[c0 + 1];
    u16 pair[2] = { f2bf(y0), f2bf(y1) };
    *(unsigned int*)(outp + (size_t)t * CDIM + c0) = *(unsigned int*)pair;
}

// ---------------------------------------------------------------------------
// QKV GEMM: 128-row block, n0-loop over 6x64 cols. Scatter into q/k/v
// [4096 win][4 head][49 n][32 hd] bf16; q *= scale.
// ---------------------------------------------------------------------------
__global__ __launch_bounds__(256) void qkv_gemm(
    const u16* __restrict__ A, const u16* __restrict__ WT,
    const float* __restrict__ bias,
    u16* __restrict__ qb, u16* __restrict__ kb, u16* __restrict__ vb)
{
    __shared__ __align__(16) short As[128 * PAD];
    __shared__ __align__(16) short Bs[64 * PAD];
    int tid = threadIdx.x;
    int m0 = blockIdx.x * 128;
    #pragma unroll
    for (int i = 0; i < 8; i++) {
        int e = i * 256 + tid; int row = e >> 4, c = e & 15;
        *(int4*)(As + row * PAD + c * 8) =
            *(const int4*)(A + (size_t)(m0 + row) * 128 + c * 8);
    }
    int w = tid >> 6, lane = tid & 63, lr = lane & 15, quad = lane >> 4;
    short8 af[2][4];
    const float scale = 0.17677669529663687f;
    for (int n0 = 0; n0 < 6; n0++) {
        #pragma unroll
        for (int i = 0; i < 4; i++) {
            int e = i * 256 + tid; int row = e >> 4, c = e & 15;
            *(int4*)(Bs + row * PAD + c * 8) =
                *(const int4*)(WT + (size_t)(n0 * 64 + row) * 128 + c * 8);
        }
        __syncthreads();
        if (n0 == 0) {
            #pragma unroll
            for (int mr = 0; mr < 2; mr++)
                #pragma unroll
                for (int ks = 0; ks < 4; ks++)
                    af[mr][ks] = *(const short8*)(As + (mr * 64 + w * 16 + lr) * PAD + ks * 32 + quad * 8);
        }
        f32x4 acc[8];
        #pragma unroll
        for (int i = 0; i < 8; i++) acc[i] = (f32x4){0.f, 0.f, 0.f, 0.f};
        #pragma unroll
        for (int ks = 0; ks < 4; ks++) {
            #pragma unroll
            for (int nt = 0; nt < 4; nt++) {
                short8 b = *(const short8*)(Bs + (nt * 16 + lr) * PAD + ks * 32 + quad * 8);
                acc[nt]     = __builtin_amdgcn_mfma_f32_16x16x32_bf16(af[0][ks], b, acc[nt], 0, 0, 0);
                acc[4 + nt] = __builtin_amdgcn_mfma_f32_16x16x32_bf16(af[1][ks], b, acc[4 + nt], 0, 0, 0);
            }
        }
        __syncthreads();
        #pragma unroll
        for (int nt = 0; nt < 4; nt++) {
            int col = n0 * 64 + nt * 16 + lr;
            int which = col >> 7, head = (col >> 5) & 3, hd = col & 31;
            u16* dst = (which == 0) ? qb : (which == 1 ? kb : vb);
            float bv = bias[col];
            #pragma unroll
            for (int mr = 0; mr < 2; mr++) {
                #pragma unroll
                for (int r = 0; r < 4; r++) {
                    int m = m0 + mr * 64 + w * 16 + quad * 4 + r;
                    int win = m / NTOK, n = m - win * NTOK;
                    float v = acc[mr * 4 + nt][r] + bv;
                    if (which == 0) v *= scale;
                    dst[(size_t)((win * 4 + head) * NTOK + n) * 32 + hd] = f2bf(v);
                }
            }
        }
    }
}

// ---------------------------------------------------------------------------
// Attention per (window, head): padded LDS (stride 33) kills bank serialization.
// ---------------------------------------------------------------------------
__global__ __launch_bounds__(256) void attn_kernel(
    const u16* __restrict__ qb, const u16* __restrict__ kb,
    const u16* __restrict__ vb, const float* __restrict__ rel_bias,
    const int* __restrict__ rel_index, const float* __restrict__ mask,
    u16* __restrict__ ob)
{
    __shared__ float qs[49 * 33], ksm[49 * 33], vs[49 * 33];
    __shared__ float S[49 * 52];
    int wh = blockIdx.x;
    int win = wh >> 2, head = wh & 3;
    int tid = threadIdx.x;
    const unsigned int* qp = (const unsigned int*)(qb + (size_t)wh * 1568);
    const unsigned int* kp = (const unsigned int*)(kb + (size_t)wh * 1568);
    const unsigned int* vp = (const unsigned int*)(vb + (size_t)wh * 1568);
    for (int u = tid; u < 784; u += 256) {
        unsigned int q2 = qp[u], k2 = kp[u], v2 = vp[u];
        int row = u >> 4, col = (u & 15) * 2;
        int o = row * 33 + col;
        qs[o]  = bf2f((u16)(q2 & 0xffff)); qs[o + 1]  = bf2f((u16)(q2 >> 16));
        ksm[o] = bf2f((u16)(k2 & 0xffff)); ksm[o + 1] = bf2f((u16)(k2 >> 16));
        vs[o]  = bf2f((u16)(v2 & 0xffff)); vs[o + 1]  = bf2f((u16)(v2 >> 16));
    }
    __syncthreads();
    const float* mrow = mask + (size_t)(win & 63) * 49 * 49;
    for (int e = tid; e < 49 * 49; e += 256) {
        int qi = e / 49, kj = e - qi * 49;
        const float* qq = qs + qi * 33;
        const float* kk = ksm + kj * 33;
        float s = 0.f;
        #pragma unroll
        for (int d = 0; d < 32; d++) s += qq[d] * kk[d];
        s += rel_bias[rel_index[e] * 4 + head];
        s += mrow[e];
        S[qi * 52 + kj] = s;
    }
    __syncthreads();
    int wave = tid >> 6, lane = tid & 63;
    for (int qi = wave; qi < 49; qi += 4) {
        float v = (lane < 49) ? S[qi * 52 + lane] : -1e30f;
        float mx = v;
        #pragma unroll
        for (int m = 1; m < 64; m <<= 1) mx = fmaxf(mx, __shfl_xor(mx, m));
        float e = (lane < 49) ? __expf(v - mx) : 0.f;
        float sum = e;
        #pragma unroll
        for (int m = 1; m < 64; m <<= 1) sum += __shfl_xor(sum, m);
        if (lane < 49) S[qi * 52 + lane] = e / sum;
    }
    __syncthreads();
    for (int e = tid; e < 49 * 32; e += 256) {
        int qi = e >> 5, hd = e & 31;
        const float* pr = S + qi * 52;
        float s = 0.f;
        #pragma unroll
        for (int kj = 0; kj < 49; kj++) s += pr[kj] * vs[kj * 33 + hd];
        ob[(size_t)(win * NTOK + qi) * CDIM + head * 32 + hd] = f2bf(s);
    }
}

// ---------------------------------------------------------------------------
// Proj GEMM + window-reverse + un-shift + residual. 128-row block, n0 over 2.
// ---------------------------------------------------------------------------
__global__ __launch_bounds__(256) void proj_gemm(
    const u16* __restrict__ A, const u16* __restrict__ WT,
    const float* __restrict__ bias, const float* __restrict__ xres,
    u16* __restrict__ x1)
{
    __shared__ __align__(16) short As[128 * PAD];
    __shared__ __align__(16) short Bs[64 * PAD];
    int tid = threadIdx.x;
    int m0 = blockIdx.x * 128;
    #pragma unroll
    for (int i = 0; i < 8; i++) {
        int e = i * 256 + tid; int row = e >> 4, c = e & 15;
        *(int4*)(As + row * PAD + c * 8) =
            *(const int4*)(A + (size_t)(m0 + row) * 128 + c * 8);
    }
    int w = tid >> 6, lane = tid & 63, lr = lane & 15, quad = lane >> 4;
    short8 af[2][4];
    for (int n0 = 0; n0 < 2; n0++) {
        #pragma unroll
        for (int i = 0; i < 4; i++) {
            int e = i * 256 + tid; int row = e >> 4, c = e & 15;
            *(int4*)(Bs + row * PAD + c * 8) =
                *(const int4*)(WT + (size_t)(n0 * 64 + row) * 128 + c * 8);
        }
        __syncthreads();
        if (n0 == 0) {
            #pragma unroll
            for (int mr = 0; mr < 2; mr++)
                #pragma unroll
                for (int ks = 0; ks < 4; ks++)
                    af[mr][ks] = *(const short8*)(As + (mr * 64 + w * 16 + lr) * PAD + ks * 32 + quad * 8);
        }
        f32x4 acc[8];
        #pragma unroll
        for (int i = 0; i < 8; i++) acc[i] = (f32x4){0.f, 0.f, 0.f, 0.f};
        #pragma unroll
        for (int ks = 0; ks < 4; ks++) {
            #pragma unroll
            for (int nt = 0; nt < 4; nt++) {
                short8 b = *(const short8*)(Bs + (nt * 16 + lr) * PAD + ks * 32 + quad * 8);
                acc[nt]     = __builtin_amdgcn_mfma_f32_16x16x32_bf16(af[0][ks], b, acc[nt], 0, 0, 0);
                acc[4 + nt] = __builtin_amdgcn_mfma_f32_16x16x32_bf16(af[1][ks], b, acc[4 + nt], 0, 0, 0);
            }
        }
        __syncthreads();
        #pragma unroll
        for (int nt = 0; nt < 4; nt++) {
            int col = n0 * 64 + nt * 16 + lr;
            float bv = bias[col];
            #pragma unroll
            for (int mr = 0; mr < 2; mr++) {
                #pragma unroll
                for (int r = 0; r < 4; r++) {
                    int m = m0 + mr * 64 + w * 16 + quad * 4 + r;
                    int win = m / NTOK, n = m - win * NTOK;
                    int b = win >> 6, wi = win & 63;
                    int hp = (wi >> 3) * WSZ + n / WSZ;
                    int wp = (wi & 7) * WSZ + n % WSZ;
                    int h = hp + SHIFT; if (h >= 56) h -= 56;
                    int ww = wp + SHIFT; if (ww >= 56) ww -= 56;
                    size_t tok = (size_t)b * 3136 + h * 56 + ww;
                    float v = acc[mr * 4 + nt][r] + bv + xres[tok * CDIM + col];
                    x1[tok * CDIM + col] = f2bf(v);
                }
            }
        }
    }
}

// ---------------------------------------------------------------------------
// MLP-in + GEGLU: n0 over 8; per n0 stage val B then gate B into same buffer.
// ---------------------------------------------------------------------------
__global__ __launch_bounds__(256) void mlpin_gemm(
    const u16* __restrict__ A, const u16* __restrict__ WT,
    const float* __restrict__ bias, u16* __restrict__ fused)
{
    __shared__ __align__(16) short As[128 * PAD];
    __shared__ __align__(16) short Bs[64 * PAD];
    int tid = threadIdx.x;
    int m0 = blockIdx.x * 128;
    #pragma unroll
    for (int i = 0; i < 8; i++) {
        int e = i * 256 + tid; int row = e >> 4, c = e & 15;
        *(int4*)(As + row * PAD + c * 8) =
            *(const int4*)(A + (size_t)(m0 + row) * 128 + c * 8);
    }
    int w = tid >> 6, lane = tid & 63, lr = lane & 15, quad = lane >> 4;
    short8 af[2][4];
    for (int n0 = 0; n0 < 8; n0++) {
        // --- val half ---
        #pragma unroll
        for (int i = 0; i < 4; i++) {
            int e = i * 256 + tid; int row = e >> 4, c = e & 15;
            *(int4*)(Bs + row * PAD + c * 8) =
                *(const int4*)(WT + (size_t)(n0 * 64 + row) * 128 + c * 8);
        }
        __syncthreads();
        if (n0 == 0) {
            #pragma unroll
            for (int mr = 0; mr < 2; mr++)
                #pragma unroll
                for (int ks = 0; ks < 4; ks++)
                    af[mr][ks] = *(const short8*)(As + (mr * 64 + w * 16 + lr) * PAD + ks * 32 + quad * 8);
        }
        f32x4 accv[8], accg[8];
        #pragma unroll
        for (int i = 0; i < 8; i++) accv[i] = (f32x4){0.f, 0.f, 0.f, 0.f};
        #pragma unroll
        for (int ks = 0; ks < 4; ks++) {
            #pragma unroll
            for (int nt = 0; nt < 4; nt++) {
                short8 b = *(const short8*)(Bs + (nt * 16 + lr) * PAD + ks * 32 + quad * 8);
                accv[nt]     = __builtin_amdgcn_mfma_f32_16x16x32_bf16(af[0][ks], b, accv[nt], 0, 0, 0);
                accv[4 + nt] = __builtin_amdgcn_mfma_f32_16x16x32_bf16(af[1][ks], b, accv[4 + nt], 0, 0, 0);
            }
        }
        __syncthreads();
        // --- gate half ---
        #pragma unroll
        for (int i = 0; i < 4; i++) {
            int e = i * 256 + tid; int row = e >> 4, c = e & 15;
            *(int4*)(Bs + row * PAD + c * 8) =
                *(const int4*)(WT + (size_t)(512 + n0 * 64 + row) * 128 + c * 8);
        }
        __syncthreads();
        #pragma unroll
        for (int i = 0; i < 8; i++) accg[i] = (f32x4){0.f, 0.f, 0.f, 0.f};
        #pragma unroll
        for (int ks = 0; ks < 4; ks++) {
            #pragma unroll
            for (int nt = 0; nt < 4; nt++) {
                short8 b = *(const short8*)(Bs + (nt * 16 + lr) * PAD + ks * 32 + quad * 8);
                accg[nt]     = __builtin_amdgcn_mfma_f32_16x16x32_bf16(af[0][ks], b, accg[nt], 0, 0, 0);
                accg[4 + nt] = __builtin_amdgcn_mfma_f32_16x16x32_bf16(af[1][ks], b, accg[4 + nt], 0, 0, 0);
            }
        }
        __syncthreads();
        #pragma unroll
        for (int nt = 0; nt < 4; nt++) {
            int col = n0 * 64 + nt * 16 + lr;
            float bv = bias[col];
            float bg = bias[512 + col];
            #pragma unroll
            for (int mr = 0; mr < 2; mr++) {
                #pragma unroll
                for (int r = 0; r < 4; r++) {
                    int m = m0 + mr * 64 + w * 16 + quad * 4 + r;
                    float x = accv[mr * 4 + nt][r] + bv;
                    float g = accg[mr * 4 + nt][r] + bg;
                    float t = tanhf(0.7978845608028654f * (x + 0.044715f * x * x * x));
                    float gel = 0.5f * x * (1.f + t);
                    float sig = 1.f / (1.f + __expf(-g));
                    fused[(size_t)m * HID + col] = f2bf(gel * sig);
                }
            }
        }
    }
}

// ---------------------------------------------------------------------------
// MLP-core + residual: K=512 via 4 kc chunks; acc for both n0 halves persists.
// ---------------------------------------------------------------------------
__global__ __launch_bounds__(256) void mlpcore_gemm(
    const u16* __restrict__ A, const u16* __restrict__ WT,
    const float* __restrict__ bias, const u16* __restrict__ x1,
    float* __restrict__ outp)
{
    __shared__ __align__(16) short As[128 * PAD];
    __shared__ __align__(16) short Bs[64 * PAD];
    int tid = threadIdx.x;
    int m0 = blockIdx.x * 128;
    int w = tid >> 6, lane = tid & 63, lr = lane & 15, quad = lane >> 4;
    f32x4 acc[16];
    #pragma unroll
    for (int i = 0; i < 16; i++) acc[i] = (f32x4){0.f, 0.f, 0.f, 0.f};
    for (int kc = 0; kc < 4; kc++) {
        #pragma unroll
        for (int i = 0; i < 8; i++) {
            int e = i * 256 + tid; int row = e >> 4, c = e & 15;
            *(int4*)(As + row * PAD + c * 8) =
                *(const int4*)(A + (size_t)(m0 + row) * HID + kc * 128 + c * 8);
        }
        #pragma unroll
        for (int i = 0; i < 4; i++) {
            int e = i * 256 + tid; int row = e >> 4, c = e & 15;
            *(int4*)(Bs + row * PAD + c * 8) =
                *(const int4*)(WT + (size_t)row * 512 + kc * 128 + c * 8);
        }
        __syncthreads();
        short8 af[2][4];
        #pragma unroll
        for (int mr = 0; mr < 2; mr++)
            #pragma unroll
            for (int ks = 0; ks < 4; ks++)
                af[mr][ks] = *(const short8*)(As + (mr * 64 + w * 16 + lr) * PAD + ks * 32 + quad * 8);
        #pragma unroll
        for (int ks = 0; ks < 4; ks++) {
            #pragma unroll
            for (int nt = 0; nt < 4; nt++) {
                short8 b = *(const short8*)(Bs + (nt * 16 + lr) * PAD + ks * 32 + quad * 8);
                acc[nt]     = __builtin_amdgcn_mfma_f32_16x16x32_bf16(af[0][ks], b, acc[nt], 0, 0, 0);
                acc[4 + nt] = __builtin_amdgcn_mfma_f32_16x16x32_bf16(af[1][ks], b, acc[4 + nt], 0, 0, 0);
            }
        }
        __syncthreads();
        #pragma unroll
        for (int i = 0; i < 4; i++) {
            int e = i * 256 + tid; int row = e >> 4, c = e & 15;
            *(int4*)(Bs + row * PAD + c * 8) =
                *(const int4*)(WT + (size_t)(64 + row) * 512 + kc * 128 + c * 8);
        }
        __syncthreads();
        #pragma unroll
        for (int ks = 0; ks < 4; ks++) {
            #pragma unroll
            for (int nt = 0; nt < 4; nt++) {
                short8 b = *(const short8*)(Bs + (nt * 16 + lr) * PAD + ks * 32 + quad * 8);
                acc[8 + nt]  = __builtin_amdgcn_mfma_f32_16x16x32_bf16(af[0][ks], b, acc[8 + nt], 0, 0, 0);
                acc[12 + nt] = __builtin_amdgcn_mfma_f32_16x16x32_bf16(af[1][ks], b, acc[12 + nt], 0, 0, 0);
            }
        }
        __syncthreads();
    }
    #pragma unroll
    for (int n0 = 0; n0 < 2; n0++) {
        #pragma unroll
        for (int nt = 0; nt < 4; nt++) {
            int col = n0 * 64 + nt * 16 + lr;
            float bv = bias[col];
            #pragma unroll
            for (int mr = 0; mr < 2; mr++) {
                #pragma unroll
                for (int r = 0; r < 4; r++) {
                    int m = m0 + mr * 64 + w * 16 + quad * 4 + r;
                    float v = acc[n0 * 8 + mr * 4 + nt][r] + bv + bf2f(x1[(size_t)m * CDIM + col]);
                    outp[(size_t)m * CDIM + col] = v;
                }
            }
        }
    }
}

// ---------------------------------------------------------------------------
extern "C" void kernel_launch(void* const* d_in, const int* in_sizes, int n_in,
                              void* d_out, int out_size, void* d_ws, size_t ws_size,
                              hipStream_t stream)
{
    const float* x        = (const float*)d_in[0];
    const float* g1       = (const float*)d_in[1];
    const float* b1       = (const float*)d_in[2];
    const float* w_qkv    = (const float*)d_in[3];
    const float* b_qkv    = (const float*)d_in[4];
    const float* rel_bias = (const float*)d_in[5];
    const float* w_proj   = (const float*)d_in[6];
    const float* b_proj   = (const float*)d_in[7];
    const float* g2       = (const float*)d_in[8];
    const float* b2       = (const float*)d_in[9];
    const float* w_in     = (const float*)d_in[10];
    const float* b_in     = (const float*)d_in[11];
    const float* w_core   = (const float*)d_in[12];
    const float* b_core   = (const float*)d_in[13];
    const float* attn_mask = (const float*)d_in[14];
    const int*   rel_index = (const int*)d_in[15];
    float* outp = (float*)d_out;

    char* ws = (char*)d_ws;
    const size_t sz128 = (size_t)T_TOK * CDIM * sizeof(u16);   // 51,380,224 B
    u16* qb    = (u16*)(ws);
    u16* kb    = (u16*)(ws + sz128);
    u16* vb    = (u16*)(ws + 2 * sz128);
    u16* ob    = (u16*)(ws + 3 * sz128);
    u16* fused = (u16*)(ws);               // reuses q/k/v/o region (dead by then)
    u16* ybuf  = (u16*)(ws + 4 * sz128);
    u16* x1    = (u16*)(ws + 5 * sz128);
    u16* qkvT  = (u16*)(ws + 6 * sz128);                 // 98304 B
    u16* projT = (u16*)(ws + 6 * sz128 + 98304);         // 32768 B
    u16* inT   = (u16*)(ws + 6 * sz128 + 131072);        // 262144 B
    u16* coreT = (u16*)(ws + 6 * sz128 + 393216);        // 131072 B

    prep_weights<<<1024, 256, 0, stream>>>(w_qkv, w_proj, w_in, w_core,
                                           qkvT, projT, inT, coreT);
    ln1_kernel<<<T_TOK / 4, 256, 0, stream>>>(x, g1, b1, ybuf);
    qkv_gemm<<<T_TOK / 128, 256, 0, stream>>>(ybuf, qkvT, b_qkv, qb, kb, vb);
    attn_kernel<<<4096 * 4, 256, 0, stream>>>(qb, kb, vb, rel_bias, rel_index, attn_mask, ob);
    proj_gemm<<<T_TOK / 128, 256, 0, stream>>>(ob, projT, b_proj, x, x1);
    ln2_kernel<<<T_TOK / 4, 256, 0, stream>>>(x1, g2, b2, ybuf);
    mlpin_gemm<<<T_TOK / 128, 256, 0, stream>>>(ybuf, inT, b_in, fused);
    mlpcore_gemm<<<T_TOK / 128, 256, 0, stream>>>(fused, coreT, b_core, x1, outp);
}

// Round 4
// 850.285 us; speedup vs baseline: 2.9422x; 1.2483x over previous
//
#include <hip/hip_runtime.h>
#include <hip/hip_bf16.h>

// ---------------------------------------------------------------------------
// TMSwinBlock v4. vs v3: attention rewritten as MFMA flash-window kernel
// (one block/window, one wave/head, QK^T and PV on matrix cores, softmax in
// registers, P transposed through padded LDS, V^T staged in padded LDS,
// rel_bias+mask pre-fused into a bf16 combo table overlaid on the x1 region).
// ---------------------------------------------------------------------------

typedef unsigned short u16;
typedef __attribute__((ext_vector_type(8))) short short8;
typedef __attribute__((ext_vector_type(4))) float f32x4;

#define T_TOK 200704   // 64*56*56
#define CDIM  128
#define NTOK  49
#define WSZ   7
#define SHIFT 3
#define HID   512
#define PAD   136      // LDS row stride in shorts for 128-wide K tiles

__device__ __forceinline__ float bf2f(u16 v) {
    return __uint_as_float(((unsigned int)v) << 16);
}
__device__ __forceinline__ u16 f2bf(float f) {
    unsigned int u = __float_as_uint(f);
    unsigned int r = 0x7FFFu + ((u >> 16) & 1u);
    return (u16)((u + r) >> 16);
}

// ---------------------------------------------------------------------------
// Weight prep: fp32 W[k][n] -> bf16 WT[n][k], all 4 weights.
// ---------------------------------------------------------------------------
__global__ __launch_bounds__(256) void prep_weights(
    const float* __restrict__ w_qkv, const float* __restrict__ w_proj,
    const float* __restrict__ w_in,  const float* __restrict__ w_core,
    u16* __restrict__ qkvT, u16* __restrict__ projT,
    u16* __restrict__ inT,  u16* __restrict__ coreT)
{
    int g = blockIdx.x * 256 + threadIdx.x;
    if (g < 49152) {                       // w_qkv 128x384
        int k = g / 384, n = g % 384;
        qkvT[n * 128 + k] = f2bf(w_qkv[g]);
    } else if (g < 65536) {                // w_proj 128x128
        int h = g - 49152; int k = h / 128, n = h % 128;
        projT[n * 128 + k] = f2bf(w_proj[h]);
    } else if (g < 196608) {               // w_in 128x1024
        int h = g - 65536; int k = h / 1024, n = h % 1024;
        inT[n * 128 + k] = f2bf(w_in[h]);
    } else {                               // w_core 512x128
        int h = g - 196608; int k = h / 128, n = h % 128;
        coreT[n * 512 + k] = f2bf(w_core[h]);
    }
}

// ---------------------------------------------------------------------------
// Combo bias table: combo[w64][head][qi][kj64] = mask + rel_bias (bf16).
// ---------------------------------------------------------------------------
__global__ __launch_bounds__(256) void prep_combo(
    const float* __restrict__ mask, const float* __restrict__ rel_bias,
    const int* __restrict__ rel_index, u16* __restrict__ combo)
{
    int g = blockIdx.x * 256 + threadIdx.x;
    if (g >= 64 * 4 * 49 * 64) return;
    int kj = g & 63;
    int qi = (g >> 6) % 49;
    int head = (g / (64 * 49)) & 3;
    int w = g / (64 * 49 * 4);
    float v = 0.f;
    if (kj < 49) {
        int e = qi * 49 + kj;
        v = mask[w * 2401 + e] + rel_bias[rel_index[e] * 4 + head];
    }
    combo[g] = f2bf(v);
}

// ---------------------------------------------------------------------------
// LN1: fp32 x -> bf16 rows in shifted-window order. One wave per token.
// ---------------------------------------------------------------------------
__global__ __launch_bounds__(256) void ln1_kernel(
    const float* __restrict__ xin, const float* __restrict__ gam,
    const float* __restrict__ bet, u16* __restrict__ outp)
{
    int wave = threadIdx.x >> 6, lane = threadIdx.x & 63;
    int t = blockIdx.x * 4 + wave;
    int win = t / NTOK, n = t - win * NTOK;
    int b = win >> 6, wi = win & 63;
    int hp = (wi >> 3) * WSZ + n / WSZ;
    int wp = (wi & 7) * WSZ + n % WSZ;
    int h = hp + SHIFT; if (h >= 56) h -= 56;
    int w = wp + SHIFT; if (w >= 56) w -= 56;
    int src = b * 3136 + h * 56 + w;
    const float* xr = xin + (size_t)src * CDIM;
    int c0 = lane * 2;
    float x0 = xr[c0], x1 = xr[c0 + 1];
    float s = x0 + x1;
    #pragma unroll
    for (int m = 1; m < 64; m <<= 1) s += __shfl_xor(s, m);
    float mean = s * (1.0f / 128.0f);
    float d0 = x0 - mean, d1 = x1 - mean;
    float v = d0 * d0 + d1 * d1;
    #pragma unroll
    for (int m = 1; m < 64; m <<= 1) v += __shfl_xor(v, m);
    float rstd = rsqrtf(v * (1.0f / 128.0f) + 1e-5f);
    float y0 = d0 * rstd * gam[c0]     + bet[c0];
    float y1 = d1 * rstd * gam[c0 + 1] + bet[c0 + 1];
    u16 pair[2] = { f2bf(y0), f2bf(y1) };
    *(unsigned int*)(outp + (size_t)t * CDIM + c0) = *(unsigned int*)pair;
}

// ---------------------------------------------------------------------------
// LN2: bf16 x1 -> bf16, identity row map.
// ---------------------------------------------------------------------------
__global__ __launch_bounds__(256) void ln2_kernel(
    const u16* __restrict__ xin, const float* __restrict__ gam,
    const float* __restrict__ bet, u16* __restrict__ outp)
{
    int wave = threadIdx.x >> 6, lane = threadIdx.x & 63;
    int t = blockIdx.x * 4 + wave;
    const u16* xr = xin + (size_t)t * CDIM;
    int c0 = lane * 2;
    float x0 = bf2f(xr[c0]), x1 = bf2f(xr[c0 + 1]);
    float s = x0 + x1;
    #pragma unroll
    for (int m = 1; m < 64; m <<= 1) s += __shfl_xor(s, m);
    float mean = s * (1.0f / 128.0f);
    float d0 = x0 - mean, d1 = x1 - mean;
    float v = d0 * d0 + d1 * d1;
    #pragma unroll
    for (int m = 1; m < 64; m <<= 1) v += __shfl_xor(v, m);
    float rstd = rsqrtf(v * (1.0f / 128.0f) + 1e-5f);
    float y0 = d0 * rstd * gam[c0]     + bet[c0];
    float y1 = d1 * rstd * gam[c0 + 1] + bet[c0 + 1];
    u16 pair[2] = { f2bf(y0), f2bf(y1) };
    *(unsigned int*)(outp + (size_t)t * CDIM + c0) = *(unsigned int*)pair;
}

// ---------------------------------------------------------------------------
// QKV GEMM: 128-row block, n0-loop over 6x64 cols. Scatter into q/k/v
// [4096 win][4 head][49 n][32 hd] bf16; q *= scale.
// ---------------------------------------------------------------------------
__global__ __launch_bounds__(256) void qkv_gemm(
    const u16* __restrict__ A, const u16* __restrict__ WT,
    const float* __restrict__ bias,
    u16* __restrict__ qb, u16* __restrict__ kb, u16* __restrict__ vb)
{
    __shared__ __align__(16) short As[128 * PAD];
    __shared__ __align__(16) short Bs[64 * PAD];
    int tid = threadIdx.x;
    int m0 = blockIdx.x * 128;
    #pragma unroll
    for (int i = 0; i < 8; i++) {
        int e = i * 256 + tid; int row = e >> 4, c = e & 15;
        *(int4*)(As + row * PAD + c * 8) =
            *(const int4*)(A + (size_t)(m0 + row) * 128 + c * 8);
    }
    int w = tid >> 6, lane = tid & 63, lr = lane & 15, quad = lane >> 4;
    short8 af[2][4];
    const float scale = 0.17677669529663687f;
    for (int n0 = 0; n0 < 6; n0++) {
        #pragma unroll
        for (int i = 0; i < 4; i++) {
            int e = i * 256 + tid; int row = e >> 4, c = e & 15;
            *(int4*)(Bs + row * PAD + c * 8) =
                *(const int4*)(WT + (size_t)(n0 * 64 + row) * 128 + c * 8);
        }
        __syncthreads();
        if (n0 == 0) {
            #pragma unroll
            for (int mr = 0; mr < 2; mr++)
                #pragma unroll
                for (int ks = 0; ks < 4; ks++)
                    af[mr][ks] = *(const short8*)(As + (mr * 64 + w * 16 + lr) * PAD + ks * 32 + quad * 8);
        }
        f32x4 acc[8];
        #pragma unroll
        for (int i = 0; i < 8; i++) acc[i] = (f32x4){0.f, 0.f, 0.f, 0.f};
        #pragma unroll
        for (int ks = 0; ks < 4; ks++) {
            #pragma unroll
            for (int nt = 0; nt < 4; nt++) {
                short8 b = *(const short8*)(Bs + (nt * 16 + lr) * PAD + ks * 32 + quad * 8);
                acc[nt]     = __builtin_amdgcn_mfma_f32_16x16x32_bf16(af[0][ks], b, acc[nt], 0, 0, 0);
                acc[4 + nt] = __builtin_amdgcn_mfma_f32_16x16x32_bf16(af[1][ks], b, acc[4 + nt], 0, 0, 0);
            }
        }
        __syncthreads();
        #pragma unroll
        for (int nt = 0; nt < 4; nt++) {
            int col = n0 * 64 + nt * 16 + lr;
            int which = col >> 7, head = (col >> 5) & 3, hd = col & 31;
            u16* dst = (which == 0) ? qb : (which == 1 ? kb : vb);
            float bv = bias[col];
            #pragma unroll
            for (int mr = 0; mr < 2; mr++) {
                #pragma unroll
                for (int r = 0; r < 4; r++) {
                    int m = m0 + mr * 64 + w * 16 + quad * 4 + r;
                    int win = m / NTOK, n = m - win * NTOK;
                    float v = acc[mr * 4 + nt][r] + bv;
                    if (which == 0) v *= scale;
                    dst[(size_t)((win * 4 + head) * NTOK + n) * 32 + hd] = f2bf(v);
                }
            }
        }
    }
}

// ---------------------------------------------------------------------------
// MFMA attention: one block per window, one wave per head.
// QK^T: Q/K fragments straight from global (layout == fragment layout).
// S in C-layout regs -> +combo -> softmax (shfl within quad) -> P bf16 via
// padded LDS (A-layout) -> PV with V^T staged in padded LDS.
// ---------------------------------------------------------------------------
__global__ __launch_bounds__(256) void attn_kernel(
    const u16* __restrict__ qb, const u16* __restrict__ kb,
    const u16* __restrict__ vb, const u16* __restrict__ combo,
    u16* __restrict__ ob)
{
    __shared__ __align__(16) short Ps[4][64 * 72];
    __shared__ __align__(16) short Vt[4][32 * 72];
    int win = blockIdx.x;
    int w = threadIdx.x >> 6;          // head
    int lane = threadIdx.x & 63;
    int lr = lane & 15, quad = lane >> 4;
    int wh = win * 4 + w;
    const u16* qp = qb + (size_t)wh * 1568;
    const u16* kp = kb + (size_t)wh * 1568;

    // stage V^T (wave-local region)
    {
        const unsigned int* vp = (const unsigned int*)(vb + (size_t)wh * 1568);
        short* vt = Vt[w];
        for (int u = lane; u < 784; u += 64) {
            unsigned int v2 = vp[u];
            int kj = u >> 4, hd2 = (u & 15) * 2;
            vt[hd2 * 72 + kj]       = (short)(v2 & 0xffff);
            vt[(hd2 + 1) * 72 + kj] = (short)(v2 >> 16);
        }
    }

    // Q (A-frag) and K (B-frag) from global; rows >=49 zero.
    short8 qa[4], kf[4];
    #pragma unroll
    for (int t = 0; t < 4; t++) {
        int row = t * 16 + lr;
        if (row < 49) {
            qa[t] = *(const short8*)(qp + row * 32 + quad * 8);
            kf[t] = *(const short8*)(kp + row * 32 + quad * 8);
        } else {
            qa[t] = (short8){0,0,0,0,0,0,0,0};
            kf[t] = (short8){0,0,0,0,0,0,0,0};
        }
    }

    // S = Q @ K^T  (16 MFMA)
    f32x4 s[4][4];
    #pragma unroll
    for (int mt = 0; mt < 4; mt++)
        #pragma unroll
        for (int nt = 0; nt < 4; nt++)
            s[mt][nt] = (f32x4){0.f, 0.f, 0.f, 0.f};
    #pragma unroll
    for (int mt = 0; mt < 4; mt++)
        #pragma unroll
        for (int nt = 0; nt < 4; nt++)
            s[mt][nt] = __builtin_amdgcn_mfma_f32_16x16x32_bf16(qa[mt], kf[nt], s[mt][nt], 0, 0, 0);

    // + combo bias, softmax per row, write P (bf16) to LDS in [qi][kj]
    const u16* cb = combo + (size_t)(((win & 63) * 4 + w) * 49) * 64;
    short* ps = Ps[w];
    #pragma unroll
    for (int mt = 0; mt < 4; mt++) {
        #pragma unroll
        for (int r = 0; r < 4; r++) {
            int qi = mt * 16 + quad * 4 + r;
            float vv[4];
            #pragma unroll
            for (int nt = 0; nt < 4; nt++) {
                int kj = nt * 16 + lr;
                float val = s[mt][nt][r];
                if (kj < 49) {
                    if (qi < 49) val += bf2f(cb[qi * 64 + kj]);
                } else {
                    val = -1e30f;
                }
                vv[nt] = val;
            }
            float mx = fmaxf(fmaxf(vv[0], vv[1]), fmaxf(vv[2], vv[3]));
            #pragma unroll
            for (int msk = 1; msk < 16; msk <<= 1) mx = fmaxf(mx, __shfl_xor(mx, msk));
            float e[4], sum = 0.f;
            #pragma unroll
            for (int nt = 0; nt < 4; nt++) { e[nt] = __expf(vv[nt] - mx); sum += e[nt]; }
            #pragma unroll
            for (int msk = 1; msk < 16; msk <<= 1) sum += __shfl_xor(sum, msk);
            float inv = 1.f / sum;
            #pragma unroll
            for (int nt = 0; nt < 4; nt++)
                ps[qi * 72 + nt * 16 + lr] = (short)f2bf(e[nt] * inv);
        }
    }
    __syncthreads();   // cheap insurance for LDS write->read visibility

    // O = P @ V  (A from Ps, B from Vt; K=64 in 2 steps; 16 MFMA)
    short8 pa[4][2], vf[2][2];
    #pragma unroll
    for (int mt = 0; mt < 4; mt++)
        #pragma unroll
        for (int kc = 0; kc < 2; kc++)
            pa[mt][kc] = *(const short8*)(ps + (mt * 16 + lr) * 72 + kc * 32 + quad * 8);
    #pragma unroll
    for (int nt = 0; nt < 2; nt++)
        #pragma unroll
        for (int kc = 0; kc < 2; kc++)
            vf[nt][kc] = *(const short8*)(Vt[w] + (nt * 16 + lr) * 72 + kc * 32 + quad * 8);
    f32x4 o[4][2];
    #pragma unroll
    for (int mt = 0; mt < 4; mt++)
        #pragma unroll
        for (int nt = 0; nt < 2; nt++) {
            o[mt][nt] = (f32x4){0.f, 0.f, 0.f, 0.f};
            #pragma unroll
            for (int kc = 0; kc < 2; kc++)
                o[mt][nt] = __builtin_amdgcn_mfma_f32_16x16x32_bf16(pa[mt][kc], vf[nt][kc], o[mt][nt], 0, 0, 0);
        }

    // store O: row qi<49, col = head*32 + nt*16+lr
    #pragma unroll
    for (int mt = 0; mt < 4; mt++) {
        #pragma unroll
        for (int r = 0; r < 4; r++) {
            int qi = mt * 16 + quad * 4 + r;
            if (qi < 49) {
                u16* orow = ob + (size_t)(win * NTOK + qi) * CDIM + w * 32;
                #pragma unroll
                for (int nt = 0; nt < 2; nt++)
                    orow[nt * 16 + lr] = f2bf(o[mt][nt][r]);
            }
        }
    }
}

// ---------------------------------------------------------------------------
// Proj GEMM + window-reverse + un-shift + residual. 128-row block, n0 over 2.
// ---------------------------------------------------------------------------
__global__ __launch_bounds__(256) void proj_gemm(
    const u16* __restrict__ A, const u16* __restrict__ WT,
    const float* __restrict__ bias, const float* __restrict__ xres,
    u16* __restrict__ x1)
{
    __shared__ __align__(16) short As[128 * PAD];
    __shared__ __align__(16) short Bs[64 * PAD];
    int tid = threadIdx.x;
    int m0 = blockIdx.x * 128;
    #pragma unroll
    for (int i = 0; i < 8; i++) {
        int e = i * 256 + tid; int row = e >> 4, c = e & 15;
        *(int4*)(As + row * PAD + c * 8) =
            *(const int4*)(A + (size_t)(m0 + row) * 128 + c * 8);
    }
    int w = tid >> 6, lane = tid & 63, lr = lane & 15, quad = lane >> 4;
    short8 af[2][4];
    for (int n0 = 0; n0 < 2; n0++) {
        #pragma unroll
        for (int i = 0; i < 4; i++) {
            int e = i * 256 + tid; int row = e >> 4, c = e & 15;
            *(int4*)(Bs + row * PAD + c * 8) =
                *(const int4*)(WT + (size_t)(n0 * 64 + row) * 128 + c * 8);
        }
        __syncthreads();
        if (n0 == 0) {
            #pragma unroll
            for (int mr = 0; mr < 2; mr++)
                #pragma unroll
                for (int ks = 0; ks < 4; ks++)
                    af[mr][ks] = *(const short8*)(As + (mr * 64 + w * 16 + lr) * PAD + ks * 32 + quad * 8);
        }
        f32x4 acc[8];
        #pragma unroll
        for (int i = 0; i < 8; i++) acc[i] = (f32x4){0.f, 0.f, 0.f, 0.f};
        #pragma unroll
        for (int ks = 0; ks < 4; ks++) {
            #pragma unroll
            for (int nt = 0; nt < 4; nt++) {
                short8 b = *(const short8*)(Bs + (nt * 16 + lr) * PAD + ks * 32 + quad * 8);
                acc[nt]     = __builtin_amdgcn_mfma_f32_16x16x32_bf16(af[0][ks], b, acc[nt], 0, 0, 0);
                acc[4 + nt] = __builtin_amdgcn_mfma_f32_16x16x32_bf16(af[1][ks], b, acc[4 + nt], 0, 0, 0);
            }
        }
        __syncthreads();
        #pragma unroll
        for (int nt = 0; nt < 4; nt++) {
            int col = n0 * 64 + nt * 16 + lr;
            float bv = bias[col];
            #pragma unroll
            for (int mr = 0; mr < 2; mr++) {
                #pragma unroll
                for (int r = 0; r < 4; r++) {
                    int m = m0 + mr * 64 + w * 16 + quad * 4 + r;
                    int win = m / NTOK, n = m - win * NTOK;
                    int b = win >> 6, wi = win & 63;
                    int hp = (wi >> 3) * WSZ + n / WSZ;
                    int wp = (wi & 7) * WSZ + n % WSZ;
                    int h = hp + SHIFT; if (h >= 56) h -= 56;
                    int ww = wp + SHIFT; if (ww >= 56) ww -= 56;
                    size_t tok = (size_t)b * 3136 + h * 56 + ww;
                    float v = acc[mr * 4 + nt][r] + bv + xres[tok * CDIM + col];
                    x1[tok * CDIM + col] = f2bf(v);
                }
            }
        }
    }
}

// ---------------------------------------------------------------------------
// MLP-in + GEGLU: n0 over 8; per n0 stage val B then gate B into same buffer.
// ---------------------------------------------------------------------------
__global__ __launch_bounds__(256) void mlpin_gemm(
    const u16* __restrict__ A, const u16* __restrict__ WT,
    const float* __restrict__ bias, u16* __restrict__ fused)
{
    __shared__ __align__(16) short As[128 * PAD];
    __shared__ __align__(16) short Bs[64 * PAD];
    int tid = threadIdx.x;
    int m0 = blockIdx.x * 128;
    #pragma unroll
    for (int i = 0; i < 8; i++) {
        int e = i * 256 + tid; int row = e >> 4, c = e & 15;
        *(int4*)(As + row * PAD + c * 8) =
            *(const int4*)(A + (size_t)(m0 + row) * 128 + c * 8);
    }
    int w = tid >> 6, lane = tid & 63, lr = lane & 15, quad = lane >> 4;
    short8 af[2][4];
    for (int n0 = 0; n0 < 8; n0++) {
        // --- val half ---
        #pragma unroll
        for (int i = 0; i < 4; i++) {
            int e = i * 256 + tid; int row = e >> 4, c = e & 15;
            *(int4*)(Bs + row * PAD + c * 8) =
                *(const int4*)(WT + (size_t)(n0 * 64 + row) * 128 + c * 8);
        }
        __syncthreads();
        if (n0 == 0) {
            #pragma unroll
            for (int mr = 0; mr < 2; mr++)
                #pragma unroll
                for (int ks = 0; ks < 4; ks++)
                    af[mr][ks] = *(const short8*)(As + (mr * 64 + w * 16 + lr) * PAD + ks * 32 + quad * 8);
        }
        f32x4 accv[8], accg[8];
        #pragma unroll
        for (int i = 0; i < 8; i++) accv[i] = (f32x4){0.f, 0.f, 0.f, 0.f};
        #pragma unroll
        for (int ks = 0; ks < 4; ks++) {
            #pragma unroll
            for (int nt = 0; nt < 4; nt++) {
                short8 b = *(const short8*)(Bs + (nt * 16 + lr) * PAD + ks * 32 + quad * 8);
                accv[nt]     = __builtin_amdgcn_mfma_f32_16x16x32_bf16(af[0][ks], b, accv[nt], 0, 0, 0);
                accv[4 + nt] = __builtin_amdgcn_mfma_f32_16x16x32_bf16(af[1][ks], b, accv[4 + nt], 0, 0, 0);
            }
        }
        __syncthreads();
        // --- gate half ---
        #pragma unroll
        for (int i = 0; i < 4; i++) {
            int e = i * 256 + tid; int row = e >> 4, c = e & 15;
            *(int4*)(Bs + row * PAD + c * 8) =
                *(const int4*)(WT + (size_t)(512 + n0 * 64 + row) * 128 + c * 8);
        }
        __syncthreads();
        #pragma unroll
        for (int i = 0; i < 8; i++) accg[i] = (f32x4){0.f, 0.f, 0.f, 0.f};
        #pragma unroll
        for (int ks = 0; ks < 4; ks++) {
            #pragma unroll
            for (int nt = 0; nt < 4; nt++) {
                short8 b = *(const short8*)(Bs + (nt * 16 + lr) * PAD + ks * 32 + quad * 8);
                accg[nt]     = __builtin_amdgcn_mfma_f32_16x16x32_bf16(af[0][ks], b, accg[nt], 0, 0, 0);
                accg[4 + nt] = __builtin_amdgcn_mfma_f32_16x16x32_bf16(af[1][ks], b, accg[4 + nt], 0, 0, 0);
            }
        }
        __syncthreads();
        #pragma unroll
        for (int nt = 0; nt < 4; nt++) {
            int col = n0 * 64 + nt * 16 + lr;
            float bv = bias[col];
            float bg = bias[512 + col];
            #pragma unroll
            for (int mr = 0; mr < 2; mr++) {
                #pragma unroll
                for (int r = 0; r < 4; r++) {
                    int m = m0 + mr * 64 + w * 16 + quad * 4 + r;
                    float x = accv[mr * 4 + nt][r] + bv;
                    float g = accg[mr * 4 + nt][r] + bg;
                    float t = tanhf(0.7978845608028654f * (x + 0.044715f * x * x * x));
                    float gel = 0.5f * x * (1.f + t);
                    float sig = 1.f / (1.f + __expf(-g));
                    fused[(size_t)m * HID + col] = f2bf(gel * sig);
                }
            }
        }
    }
}

// ---------------------------------------------------------------------------
// MLP-core + residual: K=512 via 4 kc chunks; acc for both n0 halves persists.
// ---------------------------------------------------------------------------
__global__ __launch_bounds__(256) void mlpcore_gemm(
    const u16* __restrict__ A, const u16* __restrict__ WT,
    const float* __restrict__ bias, const u16* __restrict__ x1,
    float* __restrict__ outp)
{
    __shared__ __align__(16) short As[128 * PAD];
    __shared__ __align__(16) short Bs[64 * PAD];
    int tid = threadIdx.x;
    int m0 = blockIdx.x * 128;
    int w = tid >> 6, lane = tid & 63, lr = lane & 15, quad = lane >> 4;
    f32x4 acc[16];
    #pragma unroll
    for (int i = 0; i < 16; i++) acc[i] = (f32x4){0.f, 0.f, 0.f, 0.f};
    for (int kc = 0; kc < 4; kc++) {
        #pragma unroll
        for (int i = 0; i < 8; i++) {
            int e = i * 256 + tid; int row = e >> 4, c = e & 15;
            *(int4*)(As + row * PAD + c * 8) =
                *(const int4*)(A + (size_t)(m0 + row) * HID + kc * 128 + c * 8);
        }
        #pragma unroll
        for (int i = 0; i < 4; i++) {
            int e = i * 256 + tid; int row = e >> 4, c = e & 15;
            *(int4*)(Bs + row * PAD + c * 8) =
                *(const int4*)(WT + (size_t)row * 512 + kc * 128 + c * 8);
        }
        __syncthreads();
        short8 af[2][4];
        #pragma unroll
        for (int mr = 0; mr < 2; mr++)
            #pragma unroll
            for (int ks = 0; ks < 4; ks++)
                af[mr][ks] = *(const short8*)(As + (mr * 64 + w * 16 + lr) * PAD + ks * 32 + quad * 8);
        #pragma unroll
        for (int ks = 0; ks < 4; ks++) {
            #pragma unroll
            for (int nt = 0; nt < 4; nt++) {
                short8 b = *(const short8*)(Bs + (nt * 16 + lr) * PAD + ks * 32 + quad * 8);
                acc[nt]     = __builtin_amdgcn_mfma_f32_16x16x32_bf16(af[0][ks], b, acc[nt], 0, 0, 0);
                acc[4 + nt] = __builtin_amdgcn_mfma_f32_16x16x32_bf16(af[1][ks], b, acc[4 + nt], 0, 0, 0);
            }
        }
        __syncthreads();
        #pragma unroll
        for (int i = 0; i < 4; i++) {
            int e = i * 256 + tid; int row = e >> 4, c = e & 15;
            *(int4*)(Bs + row * PAD + c * 8) =
                *(const int4*)(WT + (size_t)(64 + row) * 512 + kc * 128 + c * 8);
        }
        __syncthreads();
        #pragma unroll
        for (int ks = 0; ks < 4; ks++) {
            #pragma unroll
            for (int nt = 0; nt < 4; nt++) {
                short8 b = *(const short8*)(Bs + (nt * 16 + lr) * PAD + ks * 32 + quad * 8);
                acc[8 + nt]  = __builtin_amdgcn_mfma_f32_16x16x32_bf16(af[0][ks], b, acc[8 + nt], 0, 0, 0);
                acc[12 + nt] = __builtin_amdgcn_mfma_f32_16x16x32_bf16(af[1][ks], b, acc[12 + nt], 0, 0, 0);
            }
        }
        __syncthreads();
    }
    #pragma unroll
    for (int n0 = 0; n0 < 2; n0++) {
        #pragma unroll
        for (int nt = 0; nt < 4; nt++) {
            int col = n0 * 64 + nt * 16 + lr;
            float bv = bias[col];
            #pragma unroll
            for (int mr = 0; mr < 2; mr++) {
                #pragma unroll
                for (int r = 0; r < 4; r++) {
                    int m = m0 + mr * 64 + w * 16 + quad * 4 + r;
                    float v = acc[n0 * 8 + mr * 4 + nt][r] + bv + bf2f(x1[(size_t)m * CDIM + col]);
                    outp[(size_t)m * CDIM + col] = v;
                }
            }
        }
    }
}

// ---------------------------------------------------------------------------
extern "C" void kernel_launch(void* const* d_in, const int* in_sizes, int n_in,
                              void* d_out, int out_size, void* d_ws, size_t ws_size,
                              hipStream_t stream)
{
    const float* x        = (const float*)d_in[0];
    const float* g1       = (const float*)d_in[1];
    const float* b1       = (const float*)d_in[2];
    const float* w_qkv    = (const float*)d_in[3];
    const float* b_qkv    = (const float*)d_in[4];
    const float* rel_bias = (const float*)d_in[5];
    const float* w_proj   = (const float*)d_in[6];
    const float* b_proj   = (const float*)d_in[7];
    const float* g2       = (const float*)d_in[8];
    const float* b2       = (const float*)d_in[9];
    const float* w_in     = (const float*)d_in[10];
    const float* b_in     = (const float*)d_in[11];
    const float* w_core   = (const float*)d_in[12];
    const float* b_core   = (const float*)d_in[13];
    const float* attn_mask = (const float*)d_in[14];
    const int*   rel_index = (const int*)d_in[15];
    float* outp = (float*)d_out;

    char* ws = (char*)d_ws;
    const size_t sz128 = (size_t)T_TOK * CDIM * sizeof(u16);   // 51,380,224 B
    u16* qb    = (u16*)(ws);
    u16* kb    = (u16*)(ws + sz128);
    u16* vb    = (u16*)(ws + 2 * sz128);
    u16* ob    = (u16*)(ws + 3 * sz128);
    u16* fused = (u16*)(ws);               // reuses q/k/v/o region (dead by then)
    u16* ybuf  = (u16*)(ws + 4 * sz128);
    u16* x1    = (u16*)(ws + 5 * sz128);
    // combo overlays the x1 region: read only during attn, overwritten by proj
    u16* combo = x1;                       // 64*4*49*64*2 = 1,605,632 B
    u16* qkvT  = (u16*)(ws + 6 * sz128);                 // 98304 B
    u16* projT = (u16*)(ws + 6 * sz128 + 98304);         // 32768 B
    u16* inT   = (u16*)(ws + 6 * sz128 + 131072);        // 262144 B
    u16* coreT = (u16*)(ws + 6 * sz128 + 393216);        // 131072 B

    prep_weights<<<1024, 256, 0, stream>>>(w_qkv, w_proj, w_in, w_core,
                                           qkvT, projT, inT, coreT);
    prep_combo<<<3136, 256, 0, stream>>>(attn_mask, rel_bias, rel_index, combo);
    ln1_kernel<<<T_TOK / 4, 256, 0, stream>>>(x, g1, b1, ybuf);
    qkv_gemm<<<T_TOK / 128, 256, 0, stream>>>(ybuf, qkvT, b_qkv, qb, kb, vb);
    attn_kernel<<<4096, 256, 0, stream>>>(qb, kb, vb, combo, ob);
    proj_gemm<<<T_TOK / 128, 256, 0, stream>>>(ob, projT, b_proj, x, x1);
    ln2_kernel<<<T_TOK / 4, 256, 0, stream>>>(x1, g2, b2, ybuf);
    mlpin_gemm<<<T_TOK / 128, 256, 0, stream>>>(ybuf, inT, b_in, fused);
    mlpcore_gemm<<<T_TOK / 128, 256, 0, stream>>>(fused, coreT, b_core, x1, outp);
}